// Round 5
// baseline (904.467 us; speedup 1.0000x reference)
//
#include <hip/hip_runtime.h>
#include <hip/hip_bf16.h>

#define T_LEN 256
#define B_SZ  256
#define EMB   128
#define UNITS 100
#define GATES 400           // 4*UNITS
#define NCOL  800           // both directions: [fwd 400 | bwd 400]

typedef __attribute__((ext_vector_type(8))) short short8v;
typedef __attribute__((ext_vector_type(4))) short short4v;
typedef __attribute__((ext_vector_type(4))) float f32x4;

static __device__ __forceinline__ float bf2f(short s) {
    unsigned u = ((unsigned)(unsigned short)s) << 16;
    return __builtin_bit_cast(float, u);
}
static __device__ __forceinline__ short f2bf(float f) {
    return __builtin_bit_cast(short, __float2bfloat16(f));
}
static __device__ __forceinline__ float fast_sigmoid(float x) {
    return 1.f / (1.f + __expf(-x));
}
static __device__ __forceinline__ float fast_tanh(float x) {
    return 1.f - 2.f / (1.f + __expf(2.f * x));
}

// ---------------------------------------------------------------------------
// prep: (a) WbT[c][k] bf16 transposed word-part weights  (b) P_pos/P_dep tables
//       (c) MFMA A/B lane-layout probe -> flag
// ---------------------------------------------------------------------------
#define PREP_WT_BLOCKS 100
#define PREP_TAB_BLOCKS 107

__global__ __launch_bounds__(256) void prep(
    const float* __restrict__ Wf, const float* __restrict__ Wb,
    const float* __restrict__ bf_, const float* __restrict__ bb_,
    const float* __restrict__ Ep, const float* __restrict__ Ed,
    __hip_bfloat16* __restrict__ WbT, float* __restrict__ Ppos,
    float* __restrict__ Pdep, int* __restrict__ flag)
{
    __shared__ short Ap[16 * 32];
    __shared__ short Bp[32 * 16];

    const int bx = blockIdx.x, tid = threadIdx.x;

    if (bx < PREP_WT_BLOCKS) {
        const int base = bx * 1024 + tid * 4;
#pragma unroll
        for (int q = 0; q < 4; ++q) {
            const int id = base + q;            // id = c*128 + k
            const int c = id >> 7, k = id & 127;
            const int dir = c >= GATES;
            const int j = c - dir * GATES;
            const float* W = dir ? Wb : Wf;
            WbT[id] = __float2bfloat16(W[k * GATES + j]);
        }
    } else if (bx < PREP_WT_BLOCKS + PREP_TAB_BLOCKS) {
        const int p = bx - PREP_WT_BLOCKS;
        const bool isPos = p < 53;
        const float* Erow = isPos ? (Ep + p * EMB) : (Ed + (size_t)(p - 53) * EMB);
        const int rowoff = isPos ? EMB : 2 * EMB;
        float* dst = isPos ? (Ppos + (size_t)p * NCOL) : (Pdep + (size_t)(p - 53) * NCOL);
        for (int c = tid; c < NCOL; c += 256) {
            const int dir = c >= GATES;
            const int j = c - dir * GATES;
            const float* W = dir ? Wb : Wf;
            float s = 0.f;
            for (int k = 0; k < EMB; ++k)
                s = fmaf(Erow[k], W[(size_t)(rowoff + k) * GATES + j], s);
            if (!isPos) s += (dir ? bb_[j] : bf_[j]);
            dst[c] = s;
        }
    } else {
        // --- MFMA layout probe (wave 0 only) ---
        if (tid < 64) {
            for (int e = tid; e < 512; e += 64) {
                const int m = e >> 5, k = e & 31;
                Ap[e] = f2bf((float)((m * 3 + k * 5) % 7 - 3));
            }
            for (int e = tid; e < 512; e += 64) {
                const int k = e >> 4, n = e & 15;
                Bp[e] = f2bf((float)((k * 7 + n * 3) % 5 - 2));
            }
        }
        __syncthreads();
        if (tid < 64) {
            const int l = tid;
            const int mn = l & 15, grp = l >> 4;
            float ref[4];
#pragma unroll
            for (int i = 0; i < 4; ++i) {
                const int m = grp * 4 + i;
                float s = 0.f;
                for (int k = 0; k < 32; ++k)
                    s += bf2f(Ap[m * 32 + k]) * bf2f(Bp[k * 16 + mn]);
                ref[i] = s;
            }
            short8v a8, b8, a44, b44;
#pragma unroll
            for (int e = 0; e < 8; ++e) {
                const int k8 = grp * 8 + e;
                const int k44 = (e >> 2) * 16 + grp * 4 + (e & 3);
                a8[e]  = Ap[mn * 32 + k8];
                b8[e]  = Bp[k8 * 16 + mn];
                a44[e] = Ap[mn * 32 + k44];
                b44[e] = Bp[k44 * 16 + mn];
            }
            f32x4 z = {0.f, 0.f, 0.f, 0.f};
            f32x4 d8  = __builtin_amdgcn_mfma_f32_16x16x32_bf16(a8,  b8,  z, 0, 0, 0);
            f32x4 d44 = __builtin_amdgcn_mfma_f32_16x16x32_bf16(a44, b44, z, 0, 0, 0);
            const bool ok8  = (d8[0]  == ref[0]) && (d8[1]  == ref[1]) &&
                              (d8[2]  == ref[2]) && (d8[3]  == ref[3]);
            const bool ok44 = (d44[0] == ref[0]) && (d44[1] == ref[1]) &&
                              (d44[2] == ref[2]) && (d44[3] == ref[3]);
            const unsigned long long m8  = __ballot(ok8);
            const unsigned long long m44 = __ballot(ok44);
            if (tid == 0)
                *flag = (m8 == ~0ULL) ? 0 : ((m44 == ~0ULL) ? 1 : 1);
        }
    }
}

// ---------------------------------------------------------------------------
// embed_gemm: computes xw and stores TRANSPOSED: xwT[t][c][b]  (c = dir*400+j)
// so the lstm MFMA kernel can fragment-add it with one 8B load per tile.
// ---------------------------------------------------------------------------
#define MT 64
#define NT 160

__global__ __launch_bounds__(256) void embed_gemm(
    const int* __restrict__ words, const int* __restrict__ pos, const int* __restrict__ dep,
    const float* __restrict__ Ew, const __hip_bfloat16* __restrict__ WbT,
    const float* __restrict__ Ppos, const float* __restrict__ Pdep,
    const int* __restrict__ flag, __hip_bfloat16* __restrict__ xwT)
{
    __shared__ __align__(16) short As[MT * 128];
    __shared__ __align__(16) short Bs[NT * 128];
    __shared__ int widx[MT], pidx[MT], didx[MT];

    const int tid = threadIdx.x;
    const int bx = blockIdx.x, by = blockIdx.y;
    const int r0 = bx * MT;
    const int t = r0 >> 8, b0 = r0 & 255;
    const int n0 = by * NT;

    if (tid < MT)             widx[tid]          = words[(size_t)(b0 + tid) * T_LEN + t];
    else if (tid < 2 * MT)    pidx[tid - MT]     = pos[(size_t)(b0 + tid - MT) * T_LEN + t];
    else if (tid < 3 * MT)    didx[tid - 2 * MT] = dep[(size_t)(b0 + tid - 2 * MT) * T_LEN + t];
    __syncthreads();

#pragma unroll
    for (int q = 0; q < 4; ++q) {
        const int ch = tid + q * 256;
        const int row = ch >> 4, c16 = ch & 15;
        const float* src = Ew + (size_t)widx[row] * EMB + c16 * 8;
        const float4 v0 = *reinterpret_cast<const float4*>(src);
        const float4 v1 = *reinterpret_cast<const float4*>(src + 4);
        short8v pk;
        pk[0] = f2bf(v0.x); pk[1] = f2bf(v0.y); pk[2] = f2bf(v0.z); pk[3] = f2bf(v0.w);
        pk[4] = f2bf(v1.x); pk[5] = f2bf(v1.y); pk[6] = f2bf(v1.z); pk[7] = f2bf(v1.w);
        *reinterpret_cast<short8v*>(&As[row * 128 + ((c16 ^ (row & 7)) << 3)]) = pk;
    }
#pragma unroll
    for (int q = 0; q < 10; ++q) {
        const int ch = tid + q * 256;
        const int col = ch >> 4, c16 = ch & 15;
        const short* src = reinterpret_cast<const short*>(WbT) + (size_t)(n0 + col) * 128 + c16 * 8;
        const short8v v = *reinterpret_cast<const short8v*>(src);
        *reinterpret_cast<short8v*>(&Bs[col * 128 + ((c16 ^ (col & 7)) << 3)]) = v;
    }
    __syncthreads();

    const int w = tid >> 6, l = tid & 63;
    const int lr = l & 15, lg = l >> 4;
    const int arow = w * 16 + lr;

    f32x4 acc[10];
#pragma unroll
    for (int ni = 0; ni < 10; ++ni) acc[ni] = f32x4{0.f, 0.f, 0.f, 0.f};

    const int lay = flag[0];

    if (lay == 0) {
#pragma unroll
        for (int kk = 0; kk < 4; ++kk) {
            const int c16 = kk * 4 + lg;
            const short8v a = *reinterpret_cast<const short8v*>(
                &As[arow * 128 + ((c16 ^ (arow & 7)) << 3)]);
#pragma unroll
            for (int ni = 0; ni < 10; ++ni) {
                const int col = ni * 16 + lr;
                const short8v bfr = *reinterpret_cast<const short8v*>(
                    &Bs[col * 128 + ((c16 ^ (col & 7)) << 3)]);
                acc[ni] = __builtin_amdgcn_mfma_f32_16x16x32_bf16(a, bfr, acc[ni], 0, 0, 0);
            }
        }
    } else {
#pragma unroll
        for (int kk = 0; kk < 4; ++kk) {
            const int ch16 = kk * 4 + (lg >> 1);
            const int inner = (lg & 1) * 4;
            const int alo_i = arow * 128 + ((ch16 ^ (arow & 7)) << 3) + inner;
            const int ahi_i = arow * 128 + (((ch16 + 2) ^ (arow & 7)) << 3) + inner;
            const short4v alo = *reinterpret_cast<const short4v*>(&As[alo_i]);
            const short4v ahi = *reinterpret_cast<const short4v*>(&As[ahi_i]);
            short8v a;
            a[0] = alo[0]; a[1] = alo[1]; a[2] = alo[2]; a[3] = alo[3];
            a[4] = ahi[0]; a[5] = ahi[1]; a[6] = ahi[2]; a[7] = ahi[3];
#pragma unroll
            for (int ni = 0; ni < 10; ++ni) {
                const int col = ni * 16 + lr;
                const int blo_i = col * 128 + ((ch16 ^ (col & 7)) << 3) + inner;
                const int bhi_i = col * 128 + (((ch16 + 2) ^ (col & 7)) << 3) + inner;
                const short4v blo = *reinterpret_cast<const short4v*>(&Bs[blo_i]);
                const short4v bhi = *reinterpret_cast<const short4v*>(&Bs[bhi_i]);
                short8v b;
                b[0] = blo[0]; b[1] = blo[1]; b[2] = blo[2]; b[3] = blo[3];
                b[4] = bhi[0]; b[5] = bhi[1]; b[6] = bhi[2]; b[7] = bhi[3];
                acc[ni] = __builtin_amdgcn_mfma_f32_16x16x32_bf16(a, b, acc[ni], 0, 0, 0);
            }
        }
    }

    // epilogue: add pos/dep tables, store bf16 TRANSPOSED [t][c][b], 4 b-rows packed
    const int rbase = w * 16 + lg * 4;
    int pix[4], dix[4];
#pragma unroll
    for (int i = 0; i < 4; ++i) { pix[i] = pidx[rbase + i]; dix[i] = didx[rbase + i]; }
#pragma unroll
    for (int ni = 0; ni < 10; ++ni) {
        const int c = n0 + ni * 16 + lr;
        unsigned short s4[4];
#pragma unroll
        for (int i = 0; i < 4; ++i) {
            const float v = acc[ni][i]
                          + Ppos[(size_t)pix[i] * NCOL + c]
                          + Pdep[(size_t)dix[i] * NCOL + c];
            s4[i] = (unsigned short)f2bf(v);
        }
        uint2 pk;
        pk.x = (unsigned)s4[0] | ((unsigned)s4[1] << 16);
        pk.y = (unsigned)s4[2] | ((unsigned)s4[3] << 16);
        *reinterpret_cast<uint2*>(
            reinterpret_cast<short*>(const_cast<__hip_bfloat16*>(xwT))
            + ((size_t)t * NCOL + c) * B_SZ + b0 + rbase) = pk;
    }
}

// ---------------------------------------------------------------------------
// lstm_mfma: masked LSTM recurrence via MFMA batch tiling.
// Grid (16 batch-tiles, 2 dirs) = 32 blocks, 320 threads (5 waves).
// Per step: z[16x400] = h[16x100] @ U[100x400] + xw.
//   - U: 20 bf16 B-frags per wave, REGISTER-resident (loaded once, 80 VGPR).
//   - h: split hi/lo bf16 -> 2 MFMAs (keeps recurrence ~f32 accurate).
//   - xw: prefetched 1 step ahead from xwT[t][c][b] (8B/lane).
//   - gates: via LDS z (padded strides vs bank conflicts), c-state in regs.
// ---------------------------------------------------------------------------
#define HSTR 132            // h_sh row stride (2-way banks at A-read)
#define ZSTR 404            // z_sh row stride

__global__ __launch_bounds__(320, 1) void lstm_mfma(
    const int* __restrict__ words,
    const __hip_bfloat16* __restrict__ xwT,
    const float* __restrict__ Uf, const float* __restrict__ Ub,
    const int* __restrict__ flag,
    float* __restrict__ h_f, float* __restrict__ h_b)
{
    const int bt = blockIdx.x, dirv = blockIdx.y;
    const int b0 = bt * 16;
    const float* U = dirv ? Ub : Uf;
    float* hout    = dirv ? h_b : h_f;
    const int coff = dirv * GATES;

    __shared__ __align__(16) float h_sh[16 * HSTR];
    __shared__ float z_sh[16 * ZSTR];
    __shared__ unsigned char m_sh[16 * 256];

    const int tid = threadIdx.x;
    const int w = tid >> 6, l = tid & 63;
    const int lr = l & 15, lg = l >> 4;
    const int lay = flag[0];

    for (int i = tid; i < 16 * HSTR; i += 320) h_sh[i] = 0.f;
    for (int i = tid; i < 16 * 256; i += 320) {
        const int row = i >> 8, tt = i & 255;
        m_sh[i] = (unsigned char)(words[(size_t)(b0 + row) * T_LEN + tt] != 0);
    }

    // U B-fragments, register-resident (bf16). col = (w*5+nt)*16+lr, k padded->128.
    short8v uf[5][4];
#pragma unroll
    for (int nt = 0; nt < 5; ++nt) {
        const int col = (w * 5 + nt) * 16 + lr;
#pragma unroll
        for (int kk = 0; kk < 4; ++kk) {
#pragma unroll
            for (int e = 0; e < 8; ++e) {
                const int kl = lay ? ((e >> 2) * 16 + lg * 4 + (e & 3)) : (lg * 8 + e);
                const int k = kk * 32 + kl;
                const float v = (k < UNITS) ? U[(size_t)k * GATES + col] : 0.f;
                uf[nt][kk][e] = f2bf(v);
            }
        }
    }

    // gate-phase (row,unit) pairs: 1600 = 320 threads x 5
    int rowq[5], unitq[5], hoffq[5];
    float cq[5];
#pragma unroll
    for (int q = 0; q < 5; ++q) {
        const int p = tid + 320 * q;
        rowq[q] = p / 100;
        unitq[q] = p % 100;
        hoffq[q] = (b0 + rowq[q]) * UNITS + unitq[q];
        cq[q] = 0.f;
    }

    __syncthreads();

    const int t0 = dirv ? (T_LEN - 1) : 0;
    const int dt = dirv ? -1 : 1;

    uint2 pfA[5], pfB[5];
#pragma unroll
    for (int nt = 0; nt < 5; ++nt) {
        const int c = coff + (w * 5 + nt) * 16 + lr;
        pfA[nt] = *reinterpret_cast<const uint2*>(
            reinterpret_cast<const short*>(xwT) + ((size_t)t0 * NCOL + c) * B_SZ + b0 + lg * 4);
    }

    auto step = [&](int s, uint2 (&pfu)[5], uint2 (&pfl)[5]) {
        const int t = t0 + dt * s;
        int tn = t + dt;
        tn = (tn < 0) ? 0 : (tn > T_LEN - 1 ? T_LEN - 1 : tn);

        // prefetch next step's xw (consumed next call)
#pragma unroll
        for (int nt = 0; nt < 5; ++nt) {
            const int c = coff + (w * 5 + nt) * 16 + lr;
            pfl[nt] = *reinterpret_cast<const uint2*>(
                reinterpret_cast<const short*>(xwT) + ((size_t)tn * NCOL + c) * B_SZ + b0 + lg * 4);
        }

        f32x4 acc[5];
#pragma unroll
        for (int nt = 0; nt < 5; ++nt) acc[nt] = f32x4{0.f, 0.f, 0.f, 0.f};

        if (lay == 0) {
#pragma unroll
            for (int kk = 0; kk < 4; ++kk) {
                const int kb = kk * 32 + lg * 8;
                const float4 v0 = *reinterpret_cast<const float4*>(&h_sh[lr * HSTR + kb]);
                const float4 v1 = *reinterpret_cast<const float4*>(&h_sh[lr * HSTR + kb + 4]);
                float hv[8] = {v0.x, v0.y, v0.z, v0.w, v1.x, v1.y, v1.z, v1.w};
                short8v ahi, alo;
#pragma unroll
                for (int e = 0; e < 8; ++e) {
                    const short hi = f2bf(hv[e]);
                    ahi[e] = hi;
                    alo[e] = f2bf(hv[e] - bf2f(hi));
                }
#pragma unroll
                for (int nt = 0; nt < 5; ++nt) {
                    acc[nt] = __builtin_amdgcn_mfma_f32_16x16x32_bf16(alo, uf[nt][kk], acc[nt], 0, 0, 0);
                    acc[nt] = __builtin_amdgcn_mfma_f32_16x16x32_bf16(ahi, uf[nt][kk], acc[nt], 0, 0, 0);
                }
            }
        } else {
#pragma unroll
            for (int kk = 0; kk < 4; ++kk) {
                const int kb = kk * 32 + lg * 4;
                const float4 v0 = *reinterpret_cast<const float4*>(&h_sh[lr * HSTR + kb]);
                const float4 v1 = *reinterpret_cast<const float4*>(&h_sh[lr * HSTR + kb + 16]);
                float hv[8] = {v0.x, v0.y, v0.z, v0.w, v1.x, v1.y, v1.z, v1.w};
                short8v ahi, alo;
#pragma unroll
                for (int e = 0; e < 8; ++e) {
                    const short hi = f2bf(hv[e]);
                    ahi[e] = hi;
                    alo[e] = f2bf(hv[e] - bf2f(hi));
                }
#pragma unroll
                for (int nt = 0; nt < 5; ++nt) {
                    acc[nt] = __builtin_amdgcn_mfma_f32_16x16x32_bf16(alo, uf[nt][kk], acc[nt], 0, 0, 0);
                    acc[nt] = __builtin_amdgcn_mfma_f32_16x16x32_bf16(ahi, uf[nt][kk], acc[nt], 0, 0, 0);
                }
            }
        }

        // add xw (this step's prefetched values)
#pragma unroll
        for (int nt = 0; nt < 5; ++nt) {
            acc[nt][0] += bf2f((short)(pfu[nt].x & 0xffff));
            acc[nt][1] += bf2f((short)(pfu[nt].x >> 16));
            acc[nt][2] += bf2f((short)(pfu[nt].y & 0xffff));
            acc[nt][3] += bf2f((short)(pfu[nt].y >> 16));
        }

        // z -> LDS  (D layout: row = lg*4+i, col = tile*16+lr)
#pragma unroll
        for (int nt = 0; nt < 5; ++nt) {
            const int col = (w * 5 + nt) * 16 + lr;
#pragma unroll
            for (int i = 0; i < 4; ++i)
                z_sh[(lg * 4 + i) * ZSTR + col] = acc[nt][i];
        }
        __syncthreads();

        // gate phase: 5 (row,unit) pairs per thread
#pragma unroll
        for (int q = 0; q < 5; ++q) {
            const int row = rowq[q], unit = unitq[q];
            const float zi = z_sh[row * ZSTR + unit];
            const float zf = z_sh[row * ZSTR + UNITS + unit];
            const float zg = z_sh[row * ZSTR + 2 * UNITS + unit];
            const float zo = z_sh[row * ZSTR + 3 * UNITS + unit];
            const float ig = fast_sigmoid(zi);
            const float fg = fast_sigmoid(zf);
            const float gg = fast_tanh(zg);
            const float og = fast_sigmoid(zo);
            const float cn = fg * cq[q] + ig * gg;
            const float hn = og * fast_tanh(cn);
            const bool  m  = m_sh[row * 256 + t] != 0;
            const float hold = h_sh[row * HSTR + unit];
            const float h2 = m ? hn : hold;
            cq[q] = m ? cn : cq[q];
            h_sh[row * HSTR + unit] = h2;
            hout[(size_t)t * (B_SZ * UNITS) + hoffq[q]] = h2;
        }
        __syncthreads();
    };

    for (int s = 0; s < T_LEN; s += 2) {
        step(s, pfA, pfB);
        step(s + 1, pfB, pfA);
    }
}

// ---------------------------------------------------------------------------
// out_proj: out[b][t] = sigmoid(h_f . Wo[0:100] + h_b . Wo[100:200] + bo)
// ---------------------------------------------------------------------------
__global__ __launch_bounds__(256) void out_proj(
    const float* __restrict__ h_f, const float* __restrict__ h_b,
    const float* __restrict__ Wo, const float* __restrict__ bo,
    float* __restrict__ out)
{
    const int tid = threadIdx.x;
    const int g = tid >> 2, sub = tid & 3;
    const int r = blockIdx.x * 64 + g;      // r = t*256 + b
    const int t = r >> 8, b = r & 255;

    const float* hf = h_f + (size_t)r * UNITS;
    const float* hb = h_b + (size_t)r * UNITS;

    float s = 0.f;
    const int k0 = sub * 25;
#pragma unroll
    for (int k = 0; k < 25; ++k) s = fmaf(hf[k0 + k], Wo[k0 + k], s);
#pragma unroll
    for (int k = 0; k < 25; ++k) s = fmaf(hb[k0 + k], Wo[UNITS + k0 + k], s);

    s += __shfl_xor(s, 1);
    s += __shfl_xor(s, 2);

    if (sub == 0)
        out[(size_t)b * T_LEN + t] = 1.f / (1.f + __expf(-(s + bo[0])));
}

// ---------------------------------------------------------------------------
extern "C" void kernel_launch(void* const* d_in, const int* in_sizes, int n_in,
                              void* d_out, int out_size, void* d_ws, size_t ws_size,
                              hipStream_t stream)
{
    const int*   words = (const int*)d_in[0];
    const int*   pos   = (const int*)d_in[1];
    const int*   dep   = (const int*)d_in[2];
    const float* Ew    = (const float*)d_in[3];
    const float* Ep    = (const float*)d_in[4];
    const float* Ed    = (const float*)d_in[5];
    const float* Wf    = (const float*)d_in[6];
    const float* Uf    = (const float*)d_in[7];
    const float* bf_   = (const float*)d_in[8];
    const float* Wb    = (const float*)d_in[9];
    const float* Ub    = (const float*)d_in[10];
    const float* bb_   = (const float*)d_in[11];
    const float* Wo    = (const float*)d_in[12];
    const float* bo    = (const float*)d_in[13];
    float* out = (float*)d_out;

    auto alignup = [](size_t x) { return (x + 255) & ~(size_t)255; };
    char* p = (char*)d_ws;
    __hip_bfloat16* xwT = (__hip_bfloat16*)p; p += alignup((size_t)T_LEN * B_SZ * NCOL * 2);
    float* h_f = (float*)p;                   p += alignup((size_t)T_LEN * B_SZ * UNITS * 4);
    float* h_b = (float*)p;                   p += alignup((size_t)T_LEN * B_SZ * UNITS * 4);
    __hip_bfloat16* WbT = (__hip_bfloat16*)p; p += alignup((size_t)NCOL * 128 * 2);
    float* Ppos = (float*)p;                  p += alignup((size_t)53 * NCOL * 4);
    float* Pdep = (float*)p;                  p += alignup((size_t)54 * NCOL * 4);
    int* flag = (int*)p;

    prep<<<dim3(PREP_WT_BLOCKS + PREP_TAB_BLOCKS + 1), 256, 0, stream>>>(
        Wf, Wb, bf_, bb_, Ep, Ed, WbT, Ppos, Pdep, flag);

    embed_gemm<<<dim3((T_LEN * B_SZ) / MT, NCOL / NT), 256, 0, stream>>>(
        words, pos, dep, Ew, WbT, Ppos, Pdep, flag, xwT);

    lstm_mfma<<<dim3(B_SZ / 16, 2), 320, 0, stream>>>(
        words, xwT, Uf, Ub, flag, h_f, h_b);

    out_proj<<<dim3((T_LEN * B_SZ) / 64), 256, 0, stream>>>(h_f, h_b, Wo, bo, out);
}

// Round 6
// 834.351 us; speedup vs baseline: 1.0840x; 1.0840x over previous
//
#include <hip/hip_runtime.h>
#include <hip/hip_bf16.h>

#define T_LEN 256
#define B_SZ  256
#define EMB   128
#define UNITS 100
#define GATES 400           // 4*UNITS
#define NCOL  800           // both directions: [fwd 400 | bwd 400]

typedef __attribute__((ext_vector_type(8))) short short8v;
typedef __attribute__((ext_vector_type(4))) short short4v;
typedef __attribute__((ext_vector_type(4))) float f32x4;

static __device__ __forceinline__ float bf2f(short s) {
    unsigned u = ((unsigned)(unsigned short)s) << 16;
    return __builtin_bit_cast(float, u);
}
static __device__ __forceinline__ short f2bf(float f) {
    return __builtin_bit_cast(short, __float2bfloat16(f));
}
static __device__ __forceinline__ float fast_sigmoid(float x) {
    return 1.f / (1.f + __expf(-x));
}
static __device__ __forceinline__ float fast_tanh(float x) {
    return 1.f - 2.f / (1.f + __expf(2.f * x));
}

// ---------------------------------------------------------------------------
// prep: (a) WbT[c][k] bf16 transposed word-part weights  (b) P_pos/P_dep tables
//       (c) MFMA A/B lane-layout probe -> flag
// ---------------------------------------------------------------------------
#define PREP_WT_BLOCKS 100
#define PREP_TAB_BLOCKS 107

__global__ __launch_bounds__(256) void prep(
    const float* __restrict__ Wf, const float* __restrict__ Wb,
    const float* __restrict__ bf_, const float* __restrict__ bb_,
    const float* __restrict__ Ep, const float* __restrict__ Ed,
    __hip_bfloat16* __restrict__ WbT, float* __restrict__ Ppos,
    float* __restrict__ Pdep, int* __restrict__ flag)
{
    __shared__ short Ap[16 * 32];
    __shared__ short Bp[32 * 16];

    const int bx = blockIdx.x, tid = threadIdx.x;

    if (bx < PREP_WT_BLOCKS) {
        const int base = bx * 1024 + tid * 4;
#pragma unroll
        for (int q = 0; q < 4; ++q) {
            const int id = base + q;            // id = c*128 + k
            const int c = id >> 7, k = id & 127;
            const int dir = c >= GATES;
            const int j = c - dir * GATES;
            const float* W = dir ? Wb : Wf;
            WbT[id] = __float2bfloat16(W[k * GATES + j]);
        }
    } else if (bx < PREP_WT_BLOCKS + PREP_TAB_BLOCKS) {
        const int p = bx - PREP_WT_BLOCKS;
        const bool isPos = p < 53;
        const float* Erow = isPos ? (Ep + p * EMB) : (Ed + (size_t)(p - 53) * EMB);
        const int rowoff = isPos ? EMB : 2 * EMB;
        float* dst = isPos ? (Ppos + (size_t)p * NCOL) : (Pdep + (size_t)(p - 53) * NCOL);
        for (int c = tid; c < NCOL; c += 256) {
            const int dir = c >= GATES;
            const int j = c - dir * GATES;
            const float* W = dir ? Wb : Wf;
            float s = 0.f;
            for (int k = 0; k < EMB; ++k)
                s = fmaf(Erow[k], W[(size_t)(rowoff + k) * GATES + j], s);
            if (!isPos) s += (dir ? bb_[j] : bf_[j]);
            dst[c] = s;
        }
    } else {
        // --- MFMA layout probe (wave 0 only) ---
        if (tid < 64) {
            for (int e = tid; e < 512; e += 64) {
                const int m = e >> 5, k = e & 31;
                Ap[e] = f2bf((float)((m * 3 + k * 5) % 7 - 3));
            }
            for (int e = tid; e < 512; e += 64) {
                const int k = e >> 4, n = e & 15;
                Bp[e] = f2bf((float)((k * 7 + n * 3) % 5 - 2));
            }
        }
        __syncthreads();
        if (tid < 64) {
            const int l = tid;
            const int mn = l & 15, grp = l >> 4;
            float ref[4];
#pragma unroll
            for (int i = 0; i < 4; ++i) {
                const int m = grp * 4 + i;
                float s = 0.f;
                for (int k = 0; k < 32; ++k)
                    s += bf2f(Ap[m * 32 + k]) * bf2f(Bp[k * 16 + mn]);
                ref[i] = s;
            }
            short8v a8, b8, a44, b44;
#pragma unroll
            for (int e = 0; e < 8; ++e) {
                const int k8 = grp * 8 + e;
                const int k44 = (e >> 2) * 16 + grp * 4 + (e & 3);
                a8[e]  = Ap[mn * 32 + k8];
                b8[e]  = Bp[k8 * 16 + mn];
                a44[e] = Ap[mn * 32 + k44];
                b44[e] = Bp[k44 * 16 + mn];
            }
            f32x4 z = {0.f, 0.f, 0.f, 0.f};
            f32x4 d8  = __builtin_amdgcn_mfma_f32_16x16x32_bf16(a8,  b8,  z, 0, 0, 0);
            f32x4 d44 = __builtin_amdgcn_mfma_f32_16x16x32_bf16(a44, b44, z, 0, 0, 0);
            const bool ok8  = (d8[0]  == ref[0]) && (d8[1]  == ref[1]) &&
                              (d8[2]  == ref[2]) && (d8[3]  == ref[3]);
            const bool ok44 = (d44[0] == ref[0]) && (d44[1] == ref[1]) &&
                              (d44[2] == ref[2]) && (d44[3] == ref[3]);
            const unsigned long long m8  = __ballot(ok8);
            const unsigned long long m44 = __ballot(ok44);
            if (tid == 0)
                *flag = (m8 == ~0ULL) ? 0 : ((m44 == ~0ULL) ? 1 : 1);
        }
    }
}

// ---------------------------------------------------------------------------
// embed_gemm: computes xw and stores TRANSPOSED: xwT[t][c][b]  (c = dir*400+j)
// ---------------------------------------------------------------------------
#define MT 64
#define NT 160

__global__ __launch_bounds__(256) void embed_gemm(
    const int* __restrict__ words, const int* __restrict__ pos, const int* __restrict__ dep,
    const float* __restrict__ Ew, const __hip_bfloat16* __restrict__ WbT,
    const float* __restrict__ Ppos, const float* __restrict__ Pdep,
    const int* __restrict__ flag, __hip_bfloat16* __restrict__ xwT)
{
    __shared__ __align__(16) short As[MT * 128];
    __shared__ __align__(16) short Bs[NT * 128];
    __shared__ int widx[MT], pidx[MT], didx[MT];

    const int tid = threadIdx.x;
    const int bx = blockIdx.x, by = blockIdx.y;
    const int r0 = bx * MT;
    const int t = r0 >> 8, b0 = r0 & 255;
    const int n0 = by * NT;

    if (tid < MT)             widx[tid]          = words[(size_t)(b0 + tid) * T_LEN + t];
    else if (tid < 2 * MT)    pidx[tid - MT]     = pos[(size_t)(b0 + tid - MT) * T_LEN + t];
    else if (tid < 3 * MT)    didx[tid - 2 * MT] = dep[(size_t)(b0 + tid - 2 * MT) * T_LEN + t];
    __syncthreads();

#pragma unroll
    for (int q = 0; q < 4; ++q) {
        const int ch = tid + q * 256;
        const int row = ch >> 4, c16 = ch & 15;
        const float* src = Ew + (size_t)widx[row] * EMB + c16 * 8;
        const float4 v0 = *reinterpret_cast<const float4*>(src);
        const float4 v1 = *reinterpret_cast<const float4*>(src + 4);
        short8v pk;
        pk[0] = f2bf(v0.x); pk[1] = f2bf(v0.y); pk[2] = f2bf(v0.z); pk[3] = f2bf(v0.w);
        pk[4] = f2bf(v1.x); pk[5] = f2bf(v1.y); pk[6] = f2bf(v1.z); pk[7] = f2bf(v1.w);
        *reinterpret_cast<short8v*>(&As[row * 128 + ((c16 ^ (row & 7)) << 3)]) = pk;
    }
#pragma unroll
    for (int q = 0; q < 10; ++q) {
        const int ch = tid + q * 256;
        const int col = ch >> 4, c16 = ch & 15;
        const short* src = reinterpret_cast<const short*>(WbT) + (size_t)(n0 + col) * 128 + c16 * 8;
        const short8v v = *reinterpret_cast<const short8v*>(src);
        *reinterpret_cast<short8v*>(&Bs[col * 128 + ((c16 ^ (col & 7)) << 3)]) = v;
    }
    __syncthreads();

    const int w = tid >> 6, l = tid & 63;
    const int lr = l & 15, lg = l >> 4;
    const int arow = w * 16 + lr;

    f32x4 acc[10];
#pragma unroll
    for (int ni = 0; ni < 10; ++ni) acc[ni] = f32x4{0.f, 0.f, 0.f, 0.f};

    const int lay = flag[0];

    if (lay == 0) {
#pragma unroll
        for (int kk = 0; kk < 4; ++kk) {
            const int c16 = kk * 4 + lg;
            const short8v a = *reinterpret_cast<const short8v*>(
                &As[arow * 128 + ((c16 ^ (arow & 7)) << 3)]);
#pragma unroll
            for (int ni = 0; ni < 10; ++ni) {
                const int col = ni * 16 + lr;
                const short8v bfr = *reinterpret_cast<const short8v*>(
                    &Bs[col * 128 + ((c16 ^ (col & 7)) << 3)]);
                acc[ni] = __builtin_amdgcn_mfma_f32_16x16x32_bf16(a, bfr, acc[ni], 0, 0, 0);
            }
        }
    } else {
#pragma unroll
        for (int kk = 0; kk < 4; ++kk) {
            const int ch16 = kk * 4 + (lg >> 1);
            const int inner = (lg & 1) * 4;
            const int alo_i = arow * 128 + ((ch16 ^ (arow & 7)) << 3) + inner;
            const int ahi_i = arow * 128 + (((ch16 + 2) ^ (arow & 7)) << 3) + inner;
            const short4v alo = *reinterpret_cast<const short4v*>(&As[alo_i]);
            const short4v ahi = *reinterpret_cast<const short4v*>(&As[ahi_i]);
            short8v a;
            a[0] = alo[0]; a[1] = alo[1]; a[2] = alo[2]; a[3] = alo[3];
            a[4] = ahi[0]; a[5] = ahi[1]; a[6] = ahi[2]; a[7] = ahi[3];
#pragma unroll
            for (int ni = 0; ni < 10; ++ni) {
                const int col = ni * 16 + lr;
                const int blo_i = col * 128 + ((ch16 ^ (col & 7)) << 3) + inner;
                const int bhi_i = col * 128 + (((ch16 + 2) ^ (col & 7)) << 3) + inner;
                const short4v blo = *reinterpret_cast<const short4v*>(&Bs[blo_i]);
                const short4v bhi = *reinterpret_cast<const short4v*>(&Bs[bhi_i]);
                short8v b;
                b[0] = blo[0]; b[1] = blo[1]; b[2] = blo[2]; b[3] = blo[3];
                b[4] = bhi[0]; b[5] = bhi[1]; b[6] = bhi[2]; b[7] = bhi[3];
                acc[ni] = __builtin_amdgcn_mfma_f32_16x16x32_bf16(a, b, acc[ni], 0, 0, 0);
            }
        }
    }

    const int rbase = w * 16 + lg * 4;
    int pix[4], dix[4];
#pragma unroll
    for (int i = 0; i < 4; ++i) { pix[i] = pidx[rbase + i]; dix[i] = didx[rbase + i]; }
#pragma unroll
    for (int ni = 0; ni < 10; ++ni) {
        const int c = n0 + ni * 16 + lr;
        unsigned short s4[4];
#pragma unroll
        for (int i = 0; i < 4; ++i) {
            const float v = acc[ni][i]
                          + Ppos[(size_t)pix[i] * NCOL + c]
                          + Pdep[(size_t)dix[i] * NCOL + c];
            s4[i] = (unsigned short)f2bf(v);
        }
        uint2 pk;
        pk.x = (unsigned)s4[0] | ((unsigned)s4[1] << 16);
        pk.y = (unsigned)s4[2] | ((unsigned)s4[3] << 16);
        *reinterpret_cast<uint2*>(
            reinterpret_cast<short*>(const_cast<__hip_bfloat16*>(xwT))
            + ((size_t)t * NCOL + c) * B_SZ + b0 + rbase) = pk;
    }
}

// ---------------------------------------------------------------------------
// lstm_mfma v2: per-step critical-path rebuild.
//  - h kept in LDS as PRE-PACKED bf16 hi/lo planes, written once by the gate
//    phase; MFMA phase = pure ds_read_b128 -> MFMA (no cvt/pack on the path).
//  - raw s_barrier + lgkmcnt(0)-only (no vmcnt drain): h global stores and
//    xw prefetch stay in flight across barriers.
//  - xw double-buffered so its counted-vmcnt wait (oldest op) never drains
//    the newer h stores.
// Hazards: plane writes post-bar1 vs plane reads pre-bar1; z writes (s+1)
// vs z reads (s) separated by bar2; hout never read in this kernel.
// ---------------------------------------------------------------------------
#define HBST 136            // bf16 plane row stride (shorts): 272B = bank+4/row
#define ZSTR 404

#define BAR() do { \
    asm volatile("s_waitcnt lgkmcnt(0)" ::: "memory"); \
    __builtin_amdgcn_sched_barrier(0); \
    __builtin_amdgcn_s_barrier(); \
    __builtin_amdgcn_sched_barrier(0); \
} while (0)

__global__ __launch_bounds__(320, 1) void lstm_mfma(
    const int* __restrict__ words,
    const __hip_bfloat16* __restrict__ xwT,
    const float* __restrict__ Uf, const float* __restrict__ Ub,
    const int* __restrict__ flag,
    float* __restrict__ h_f, float* __restrict__ h_b)
{
    const int bt = blockIdx.x, dirv = blockIdx.y;
    const int b0 = bt * 16;
    const float* U = dirv ? Ub : Uf;
    float* hout    = dirv ? h_b : h_f;
    const int coff = dirv * GATES;

    __shared__ __align__(16) short hs_hi[16 * HBST];
    __shared__ __align__(16) short hs_lo[16 * HBST];
    __shared__ float z_sh[16 * ZSTR];
    __shared__ unsigned char m_sh[16 * 256];

    const int tid = threadIdx.x;
    const int w = tid >> 6, l = tid & 63;
    const int lr = l & 15, lg = l >> 4;
    const int lay = flag[0];

    for (int i = tid; i < 16 * HBST; i += 320) { hs_hi[i] = 0; hs_lo[i] = 0; }
    for (int i = tid; i < 16 * 256; i += 320) {
        const int row = i >> 8, tt = i & 255;
        m_sh[i] = (unsigned char)(words[(size_t)(b0 + row) * T_LEN + tt] != 0);
    }

    // U B-fragments, register-resident bf16: 5 col-tiles x 4 k-blocks.
    short8v uf[5][4];
#pragma unroll
    for (int nt = 0; nt < 5; ++nt) {
        const int col = (w * 5 + nt) * 16 + lr;
#pragma unroll
        for (int kk = 0; kk < 4; ++kk) {
#pragma unroll
            for (int e = 0; e < 8; ++e) {
                const int kl = lay ? ((e >> 2) * 16 + lg * 4 + (e & 3)) : (lg * 8 + e);
                const int k = kk * 32 + kl;
                const float v = (k < UNITS) ? U[(size_t)k * GATES + col] : 0.f;
                uf[nt][kk][e] = f2bf(v);
            }
        }
    }

    // per-thread gate state: (row,unit) pairs, 1600 = 320 x 5
    float cq[5], hq[5];
    int zoff[5], moff[5], hpoff[5], goff[5];
#pragma unroll
    for (int q = 0; q < 5; ++q) {
        const int p = tid + 320 * q;
        const int row = p / 100, unit = p % 100;
        zoff[q]  = row * ZSTR + unit;
        moff[q]  = row * 256;
        hpoff[q] = row * HBST + unit;
        goff[q]  = (b0 + row) * UNITS + unit;
        cq[q] = 0.f; hq[q] = 0.f;
    }

    __syncthreads();

    const int t0 = dirv ? (T_LEN - 1) : 0;
    const int dt = dirv ? -1 : 1;

    const short* xws = reinterpret_cast<const short*>(xwT);
    int cols[5];
#pragma unroll
    for (int nt = 0; nt < 5; ++nt) cols[nt] = coff + (w * 5 + nt) * 16 + lr;

    uint2 pf_cur[5], pf_nxt[5];
#pragma unroll
    for (int nt = 0; nt < 5; ++nt)
        pf_cur[nt] = *reinterpret_cast<const uint2*>(
            xws + ((size_t)t0 * NCOL + cols[nt]) * B_SZ + b0 + lg * 4);

    for (int s = 0; s < T_LEN; ++s) {
        const int t = t0 + dt * s;
        int tn = t + dt; tn = tn < 0 ? 0 : (tn >= T_LEN ? T_LEN - 1 : tn);

        // prefetch next step's xw (used next iteration)
#pragma unroll
        for (int nt = 0; nt < 5; ++nt)
            pf_nxt[nt] = *reinterpret_cast<const uint2*>(
                xws + ((size_t)tn * NCOL + cols[nt]) * B_SZ + b0 + lg * 4);

        f32x4 acc[5];
#pragma unroll
        for (int nt = 0; nt < 5; ++nt) acc[nt] = f32x4{0.f, 0.f, 0.f, 0.f};

#pragma unroll
        for (int kk = 0; kk < 4; ++kk) {
            short8v ahi, alo;
            if (lay == 0) {
                ahi = *reinterpret_cast<const short8v*>(&hs_hi[lr * HBST + kk * 32 + lg * 8]);
                alo = *reinterpret_cast<const short8v*>(&hs_lo[lr * HBST + kk * 32 + lg * 8]);
            } else {
                const short4v h0 = *reinterpret_cast<const short4v*>(&hs_hi[lr * HBST + kk * 32 + lg * 4]);
                const short4v h1 = *reinterpret_cast<const short4v*>(&hs_hi[lr * HBST + kk * 32 + 16 + lg * 4]);
                const short4v l0 = *reinterpret_cast<const short4v*>(&hs_lo[lr * HBST + kk * 32 + lg * 4]);
                const short4v l1 = *reinterpret_cast<const short4v*>(&hs_lo[lr * HBST + kk * 32 + 16 + lg * 4]);
                ahi[0] = h0[0]; ahi[1] = h0[1]; ahi[2] = h0[2]; ahi[3] = h0[3];
                ahi[4] = h1[0]; ahi[5] = h1[1]; ahi[6] = h1[2]; ahi[7] = h1[3];
                alo[0] = l0[0]; alo[1] = l0[1]; alo[2] = l0[2]; alo[3] = l0[3];
                alo[4] = l1[0]; alo[5] = l1[1]; alo[6] = l1[2]; alo[7] = l1[3];
            }
#pragma unroll
            for (int nt = 0; nt < 5; ++nt) {
                acc[nt] = __builtin_amdgcn_mfma_f32_16x16x32_bf16(alo, uf[nt][kk], acc[nt], 0, 0, 0);
                acc[nt] = __builtin_amdgcn_mfma_f32_16x16x32_bf16(ahi, uf[nt][kk], acc[nt], 0, 0, 0);
            }
        }

        // xw add + z -> LDS
#pragma unroll
        for (int nt = 0; nt < 5; ++nt) {
            acc[nt][0] += bf2f((short)(pf_cur[nt].x & 0xffff));
            acc[nt][1] += bf2f((short)(pf_cur[nt].x >> 16));
            acc[nt][2] += bf2f((short)(pf_cur[nt].y & 0xffff));
            acc[nt][3] += bf2f((short)(pf_cur[nt].y >> 16));
            const int col = cols[nt] - coff;
#pragma unroll
            for (int i = 0; i < 4; ++i)
                z_sh[(lg * 4 + i) * ZSTR + col] = acc[nt][i];
        }

        BAR();

        // gate phase
#pragma unroll
        for (int q = 0; q < 5; ++q) {
            const float zi = z_sh[zoff[q]];
            const float zf = z_sh[zoff[q] + UNITS];
            const float zg = z_sh[zoff[q] + 2 * UNITS];
            const float zo = z_sh[zoff[q] + 3 * UNITS];
            const float ig = fast_sigmoid(zi);
            const float fg = fast_sigmoid(zf);
            const float gg = fast_tanh(zg);
            const float og = fast_sigmoid(zo);
            const float cn = fg * cq[q] + ig * gg;
            const float hn = og * fast_tanh(cn);
            const bool  m  = m_sh[moff[q] + t] != 0;
            const float h2 = m ? hn : hq[q];
            cq[q] = m ? cn : cq[q];
            hq[q] = h2;
            const short hi = f2bf(h2);
            hs_hi[hpoff[q]] = hi;
            hs_lo[hpoff[q]] = f2bf(h2 - bf2f(hi));
            hout[(size_t)t * (B_SZ * UNITS) + goff[q]] = h2;
        }

        BAR();

#pragma unroll
        for (int nt = 0; nt < 5; ++nt) pf_cur[nt] = pf_nxt[nt];
    }
}

// ---------------------------------------------------------------------------
// out_proj: out[b][t] = sigmoid(h_f . Wo[0:100] + h_b . Wo[100:200] + bo)
// ---------------------------------------------------------------------------
__global__ __launch_bounds__(256) void out_proj(
    const float* __restrict__ h_f, const float* __restrict__ h_b,
    const float* __restrict__ Wo, const float* __restrict__ bo,
    float* __restrict__ out)
{
    const int tid = threadIdx.x;
    const int g = tid >> 2, sub = tid & 3;
    const int r = blockIdx.x * 64 + g;      // r = t*256 + b
    const int t = r >> 8, b = r & 255;

    const float* hf = h_f + (size_t)r * UNITS;
    const float* hb = h_b + (size_t)r * UNITS;

    float s = 0.f;
    const int k0 = sub * 25;
#pragma unroll
    for (int k = 0; k < 25; ++k) s = fmaf(hf[k0 + k], Wo[k0 + k], s);
#pragma unroll
    for (int k = 0; k < 25; ++k) s = fmaf(hb[k0 + k], Wo[UNITS + k0 + k], s);

    s += __shfl_xor(s, 1);
    s += __shfl_xor(s, 2);

    if (sub == 0)
        out[(size_t)b * T_LEN + t] = 1.f / (1.f + __expf(-(s + bo[0])));
}

// ---------------------------------------------------------------------------
extern "C" void kernel_launch(void* const* d_in, const int* in_sizes, int n_in,
                              void* d_out, int out_size, void* d_ws, size_t ws_size,
                              hipStream_t stream)
{
    const int*   words = (const int*)d_in[0];
    const int*   pos   = (const int*)d_in[1];
    const int*   dep   = (const int*)d_in[2];
    const float* Ew    = (const float*)d_in[3];
    const float* Ep    = (const float*)d_in[4];
    const float* Ed    = (const float*)d_in[5];
    const float* Wf    = (const float*)d_in[6];
    const float* Uf    = (const float*)d_in[7];
    const float* bf_   = (const float*)d_in[8];
    const float* Wb    = (const float*)d_in[9];
    const float* Ub    = (const float*)d_in[10];
    const float* bb_   = (const float*)d_in[11];
    const float* Wo    = (const float*)d_in[12];
    const float* bo    = (const float*)d_in[13];
    float* out = (float*)d_out;

    auto alignup = [](size_t x) { return (x + 255) & ~(size_t)255; };
    char* p = (char*)d_ws;
    __hip_bfloat16* xwT = (__hip_bfloat16*)p; p += alignup((size_t)T_LEN * B_SZ * NCOL * 2);
    float* h_f = (float*)p;                   p += alignup((size_t)T_LEN * B_SZ * UNITS * 4);
    float* h_b = (float*)p;                   p += alignup((size_t)T_LEN * B_SZ * UNITS * 4);
    __hip_bfloat16* WbT = (__hip_bfloat16*)p; p += alignup((size_t)NCOL * 128 * 2);
    float* Ppos = (float*)p;                  p += alignup((size_t)53 * NCOL * 4);
    float* Pdep = (float*)p;                  p += alignup((size_t)54 * NCOL * 4);
    int* flag = (int*)p;

    prep<<<dim3(PREP_WT_BLOCKS + PREP_TAB_BLOCKS + 1), 256, 0, stream>>>(
        Wf, Wb, bf_, bb_, Ep, Ed, WbT, Ppos, Pdep, flag);

    embed_gemm<<<dim3((T_LEN * B_SZ) / MT, NCOL / NT), 256, 0, stream>>>(
        words, pos, dep, Ew, WbT, Ppos, Pdep, flag, xwT);

    lstm_mfma<<<dim3(B_SZ / 16, 2), 320, 0, stream>>>(
        words, xwT, Uf, Ub, flag, h_f, h_b);

    out_proj<<<dim3((T_LEN * B_SZ) / 64), 256, 0, stream>>>(h_f, h_b, Wo, bo, out);
}